// Round 14
// baseline (488.709 us; speedup 1.0000x reference)
//
#include <hip/hip_runtime.h>
#include <stdint.h>
#include <math.h>

// Problem constants
#define NTOK 4096   // B*S
#define H    1024
#define NHEAD 16
#define HD   64
#define SEQ  2048
#define NE   8
#define DDIM 1024

typedef __attribute__((ext_vector_type(4)))  int i32x4;
typedef __attribute__((ext_vector_type(16))) int i32x16;
typedef __attribute__((ext_vector_type(8)))  short bf16x8;
typedef __attribute__((ext_vector_type(4)))  float f32x4;

#define LOG2E 1.4426950408889634f

// ---------------- helpers ----------------

__device__ __forceinline__ i32x16 mfma_i8(i32x4 a, i32x4 b, i32x16 c) {
  return __builtin_amdgcn_mfma_i32_32x32x32_i8(a, b, c, 0, 0, 0);
}

// async global->LDS direct copy, 16B per lane (dest = uniform base + lane*16)
__device__ __forceinline__ void gload16(const void* g, void* l) {
  __builtin_amdgcn_global_load_lds((const unsigned int*)g, (unsigned int*)l, 16, 0, 0);
}

// float -> bf16 round-to-nearest-even (finite inputs)
__device__ __forceinline__ unsigned int f2bf(float f) {
  unsigned int u = __float_as_uint(f);
  return (u + 0x7fffu + ((u >> 16) & 1u)) >> 16;
}
__device__ __forceinline__ float bf2f(unsigned int b) {
  return __uint_as_float(b << 16);
}
// pack hi-parts of (a,b) into return, lo-parts (residual bf16) into lo
__device__ __forceinline__ unsigned int f2bf2hl(float a, float b, unsigned int& lo) {
  unsigned int ha = f2bf(a), hb = f2bf(b);
  lo = f2bf(a - bf2f(ha)) | (f2bf(b - bf2f(hb)) << 16);
  return ha | (hb << 16);
}
// pack double-bf16 pair of one float: low ushort = hi, high ushort = lo
__device__ __forceinline__ unsigned int fpair(float a) {
  unsigned int hi = f2bf(a);
  unsigned int lo = f2bf(a - bf2f(hi));
  return hi | (lo << 16);
}
__device__ __forceinline__ unsigned int ror16(unsigned int x) {
  return (x >> 16) | (x << 16);
}

// 256-thread block reduce (double). op=0 sum, op=1 max. tmp: __shared__ double[4]
__device__ __forceinline__ double bredd(double v, int op, double* tmp) {
#pragma unroll
  for (int o = 32; o; o >>= 1) {
    double w = __shfl_xor(v, o);
    v = op ? fmax(v, w) : v + w;
  }
  int wid = threadIdx.x >> 6;
  if ((threadIdx.x & 63) == 0) tmp[wid] = v;
  __syncthreads();
  double r = op ? fmax(fmax(tmp[0], tmp[1]), fmax(tmp[2], tmp[3]))
                : (tmp[0] + tmp[1] + tmp[2] + tmp[3]);
  __syncthreads();
  return r;
}

// quantize 4 doubles to packed int8 with double scale (round-half-even like jnp.round)
__device__ __forceinline__ int qpackd(double n0, double n1, double n2, double n3, double s) {
  int a = (int)fmin(fmax(rint(n0 * s), -128.0), 127.0);
  int b = (int)fmin(fmax(rint(n1 * s), -128.0), 127.0);
  int c = (int)fmin(fmax(rint(n2 * s), -128.0), 127.0);
  int d = (int)fmin(fmax(rint(n3 * s), -128.0), 127.0);
  return (a & 255) | ((b & 255) << 8) | ((c & 255) << 16) | ((d & 255) << 24);
}

// map flat tensor id (0..27, each 1M elems) -> source pointer
__device__ __forceinline__ const float* wsrc(int tensor,
    const float* qw_, const float* kw_, const float* vw_, const float* ow_,
    const float* gw_, const float* uw_, const float* dw_) {
  if (tensor < 4) return tensor == 0 ? qw_ : tensor == 1 ? kw_ : tensor == 2 ? vw_ : ow_;
  if (tensor < 12) return gw_ + ((long long)(tensor - 4) << 20);
  if (tensor < 20) return uw_ + ((long long)(tensor - 12) << 20);
  return dw_ + ((long long)(tensor - 20) << 20);
}

// ---------------- weight quantization (fp64 scale, deterministic) ----------------

__global__ __launch_bounds__(256) void k_absum(
    const float* qw_, const float* kw_, const float* vw_, const float* ow_,
    const float* gw_, const float* uw_, const float* dw_, double* partial) {
  __shared__ double tmp[4];
  int tensor = blockIdx.x >> 10;
  int j = ((blockIdx.x & 1023) << 10) + threadIdx.x * 4;
  const float* src = wsrc(tensor, qw_, kw_, vw_, ow_, gw_, uw_, dw_);
  float4 w = *(const float4*)(src + j);
  double v = fabs((double)w.x) + fabs((double)w.y) + fabs((double)w.z) + fabs((double)w.w);
  v = bredd(v, 0, tmp);
  if (threadIdx.x == 0) partial[blockIdx.x] = v;
}

__global__ __launch_bounds__(256) void k_wscale(const double* partial, double* wsd) {
  __shared__ double tmp[4];
  int tensor = blockIdx.x;
  const double* p = partial + (tensor << 10);
  int i = threadIdx.x * 4;
  double v = p[i] + p[i + 1] + p[i + 2] + p[i + 3];
  v = bredd(v, 0, tmp);
  if (threadIdx.x == 0) wsd[tensor] = 1.0 / fmax(v * (1.0 / 1048576.0), 1e-5);
}

__global__ __launch_bounds__(256) void k_quantw(
    const float* qw_, const float* kw_, const float* vw_, const float* ow_,
    const float* gw_, const float* uw_, const float* dw_,
    const double* wsd, int8_t* qw) {
  int tensor = blockIdx.x >> 10;
  int j = ((blockIdx.x & 1023) << 10) + threadIdx.x * 4;
  const float* src = wsrc(tensor, qw_, kw_, vw_, ow_, gw_, uw_, dw_);
  double s = wsd[tensor];
  float4 w = *(const float4*)(src + j);
  int a = (int)fmin(fmax(rint((double)w.x * s), -1.0), 1.0);
  int b = (int)fmin(fmax(rint((double)w.y * s), -1.0), 1.0);
  int c = (int)fmin(fmax(rint((double)w.z * s), -1.0), 1.0);
  int d = (int)fmin(fmax(rint((double)w.w * s), -1.0), 1.0);
  ((int*)qw)[(tensor << 18) + (j >> 2)] =
      (a & 255) | ((b & 255) << 8) | ((c & 255) << 16) | ((d & 255) << 24);
}

// ---------------- rmsnorm + act_quant (attention input), fp64 decisions ----------------

__global__ __launch_bounds__(256) void k_rms1(const float* X, const float* lnw,
                                              int8_t* xq, double* xsd) {
  __shared__ double tmp[4];
  int t = blockIdx.x, tid = threadIdx.x;
  float4 xv = ((const float4*)(X + (long long)t * H))[tid];
  double x0 = xv.x, x1 = xv.y, x2 = xv.z, x3 = xv.w;
  double ss = x0 * x0 + x1 * x1 + x2 * x2 + x3 * x3;
  ss = bredd(ss, 0, tmp);
  double r = 1.0 / sqrt(ss * (1.0 / 1024.0) + 1e-5);
  float4 wv = ((const float4*)lnw)[tid];
  double n0 = x0 * r * wv.x, n1 = x1 * r * wv.y, n2 = x2 * r * wv.z, n3 = x3 * r * wv.w;
  double ma = fmax(fmax(fabs(n0), fabs(n1)), fmax(fabs(n2), fabs(n3)));
  ma = bredd(ma, 1, tmp);
  double s = 127.0 / fmax(ma, 1e-5);
  ((int*)xq)[t * 256 + tid] = qpackd(n0, n1, n2, n3, s);
  if (tid == 0) xsd[t] = s;
}

// act_quant only (rows of 1024 floats), fp64 decisions
__global__ __launch_bounds__(256) void k_actq(const float* X, int8_t* xq, double* xsd) {
  __shared__ double tmp[4];
  int t = blockIdx.x, tid = threadIdx.x;
  float4 xv = ((const float4*)(X + (long long)t * H))[tid];
  double x0 = xv.x, x1 = xv.y, x2 = xv.z, x3 = xv.w;
  double ma = fmax(fmax(fabs(x0), fabs(x1)), fmax(fabs(x2), fabs(x3)));
  ma = bredd(ma, 1, tmp);
  double s = 127.0 / fmax(ma, 1e-5);
  ((int*)xq)[t * 256 + tid] = qpackd(x0, x1, x2, x3, s);
  if (tid == 0) xsd[t] = s;
}

// ---------------- int8 GEMM via MFMA (o-proj): out = res + acc/(xs*sw) ----------
// BM=64 BN=128 BK=64 -> 512 blocks = 2/CU. R20: global_load_lds staging
// (unit v at LDS offset v*16; Xs[4][64]: v = kc*64+row; Ws[4][128]: kc*128+row).
// Bit-identical data in identical LDS slots.

__global__ __launch_bounds__(256) void k_gemm(
    const int8_t* __restrict__ Xq, const double* __restrict__ xsd,
    const int8_t* __restrict__ W, const double* __restrict__ wsd, int widx,
    const float* __restrict__ residual, float* __restrict__ out) {
  __shared__ i32x4 Xs[4][64];
  __shared__ i32x4 Ws[4][128];
  __shared__ double invs[64];
  int tid = threadIdx.x;
  int t0 = blockIdx.y * 64, n0 = blockIdx.x * 128;
  int w = tid >> 6, lane = tid & 63;
  int lrow = lane & 31, lk = lane >> 5;
  i32x4* XsU = &Xs[0][0];
  i32x4* WsU = &Ws[0][0];
  int xv_ = w * 64 + lane;          // X unit 0..255
  int xrow_g = xv_ & 63, xkc_g = xv_ >> 6;
  const int8_t* xsrc = Xq + (long long)(t0 + xrow_g) * 1024 + xkc_g * 16;
  i32x16 acc[2];
#pragma unroll
  for (int i = 0; i < 2; i++)
#pragma unroll
    for (int r = 0; r < 16; r++) acc[i][r] = 0;

  for (int k0 = 0; k0 < 1024; k0 += 64) {
    gload16(xsrc + k0, XsU + w * 64);
#pragma unroll
    for (int j = 0; j < 2; j++) {
      int vb = w * 128 + j * 64;
      int v = vb + lane;
      int row = v & 127, kc = v >> 7;
      gload16(W + (long long)(n0 + row) * 1024 + k0 + kc * 16, WsU + vb);
    }
    __syncthreads();
#pragma unroll
    for (int ks = 0; ks < 2; ks++) {
      i32x4 a0 = Xs[ks * 2 + lk][lrow];
      i32x4 a1 = Xs[ks * 2 + lk][32 + lrow];
      i32x4 b  = Ws[ks * 2 + lk][w * 32 + lrow];
      acc[0] = mfma_i8(a0, b, acc[0]);
      acc[1] = mfma_i8(a1, b, acc[1]);
    }
    __syncthreads();
  }

  double sw = wsd[widx];
  if (tid < 64) invs[tid] = 1.0 / (xsd[t0 + tid] * sw);
  __syncthreads();
  int n = n0 + w * 32 + lrow;
#pragma unroll
  for (int i = 0; i < 2; i++) {
#pragma unroll
    for (int r = 0; r < 16; r++) {
      int rl = i * 32 + (r & 3) + 8 * (r >> 2) + 4 * lk;
      int trow = t0 + rl;
      double v = (double)acc[i][r] * invs[rl];
      if (residual) v += (double)residual[(long long)trow * H + n];
      out[(long long)trow * H + n] = (float)v;
    }
  }
}

// k_gemm3: fused q/k/v projections writing ATTENTION-NATIVE formats:
//   z==0 (q): fp32 qbuf; z==1 (k): split double-bf16 planes Kh/Kl;
//   z==2 (v): interleaved pair words Vp (fpair). R20: global_load_lds staging.

__global__ __launch_bounds__(256) void k_gemm3(
    const int8_t* __restrict__ Xq, const double* __restrict__ xsd,
    const int8_t* __restrict__ qw, const double* __restrict__ wsd,
    float* __restrict__ outq, unsigned short* __restrict__ Kh,
    unsigned short* __restrict__ Kl, unsigned int* __restrict__ Vp) {
  __shared__ i32x4 Xs[4][128];
  __shared__ i32x4 Ws[4][128];
  __shared__ double invs[128];
  int z = blockIdx.z;
  const int8_t* W = qw + ((long long)z << 20);
  int tid = threadIdx.x;
  int t0 = blockIdx.y * 128, n0 = blockIdx.x * 128;
  int w = tid >> 6, lane = tid & 63;
  int wm = w >> 1, wn = w & 1;
  int lrow = lane & 31, lk = lane >> 5;
  i32x4* XsU = &Xs[0][0];
  i32x4* WsU = &Ws[0][0];
  i32x16 acc[2][2];
#pragma unroll
  for (int i = 0; i < 2; i++)
#pragma unroll
    for (int j = 0; j < 2; j++)
#pragma unroll
      for (int r = 0; r < 16; r++) acc[i][j][r] = 0;

  for (int k0 = 0; k0 < 1024; k0 += 64) {
#pragma unroll
    for (int j = 0; j < 2; j++) {
      int vb = w * 128 + j * 64;
      int v = vb + lane;
      int row = v & 127, kc = v >> 7;
      gload16(Xq + (long long)(t0 + row) * 1024 + k0 + kc * 16, XsU + vb);
      gload16(W  + (long long)(n0 + row) * 1024 + k0 + kc * 16, WsU + vb);
    }
    __syncthreads();
#pragma unroll
    for (int ks = 0; ks < 2; ks++) {
      i32x4 a0 = Xs[ks * 2 + lk][wm * 64 + lrow];
      i32x4 a1 = Xs[ks * 2 + lk][wm * 64 + 32 + lrow];
      i32x4 b0 = Ws[ks * 2 + lk][wn * 64 + lrow];
      i32x4 b1 = Ws[ks * 2 + lk][wn * 64 + 32 + lrow];
      acc[0][0] = mfma_i8(a0, b0, acc[0][0]);
      acc[0][1] = mfma_i8(a0, b1, acc[0][1]);
      acc[1][0] = mfma_i8(a1, b0, acc[1][0]);
      acc[1][1] = mfma_i8(a1, b1, acc[1][1]);
    }
    __syncthreads();
  }

  double sw = wsd[z];
  if (tid < 128) invs[tid] = 1.0 / (xsd[t0 + tid] * sw);
  __syncthreads();
#pragma unroll
  for (int i = 0; i < 2; i++) {
#pragma unroll
    for (int r = 0; r < 16; r++) {
      int rloc = wm * 64 + i * 32 + (r & 3) + 8 * (r >> 2) + 4 * lk;
      long long base = (long long)(t0 + rloc) * H;
      double inv = invs[rloc];
#pragma unroll
      for (int j = 0; j < 2; j++) {
        int n = n0 + wn * 64 + j * 32 + lrow;
        float vf = (float)((double)acc[i][j][r] * inv);
        long long idx = base + n;
        if (z == 0) {
          outq[idx] = vf;
        } else if (z == 1) {
          unsigned int h = f2bf(vf);
          unsigned int l = f2bf(vf - bf2f(h));
          Kh[idx] = (unsigned short)h;
          Kl[idx] = (unsigned short)l;
        } else {
          Vp[idx] = fpair(vf);
        }
      }
    }
  }
}

// ---------------- attention ----------------
// k_knorm: per-(b,head) max key L2-norm from packed Kh/Kl (reconstruct h+l).

__global__ __launch_bounds__(256) void k_knorm(const unsigned short* __restrict__ Kh,
                                               const unsigned short* __restrict__ Kl,
                                               float* __restrict__ Mk) {
  __shared__ float tmp[4];
  int bh = blockIdx.x;          // b*16 + head
  int b = bh >> 4, head = bh & 15;
  int tid = threadIdx.x;
  float mx = 0.f;
  for (int key = tid; key < SEQ; key += 256) {
    long long base = ((long long)(b * SEQ + key)) * H + head * HD;
    const uint4* hq4 = (const uint4*)(Kh + base);
    const uint4* lq4 = (const uint4*)(Kl + base);
    float s = 0.f;
#pragma unroll
    for (int i = 0; i < 8; i++) {         // 8 x (8 ushorts) = 64 elems
      uint4 hu = hq4[i], lu = lq4[i];
      const unsigned int hw[4] = {hu.x, hu.y, hu.z, hu.w};
      const unsigned int lw[4] = {lu.x, lu.y, lu.z, lu.w};
#pragma unroll
      for (int j = 0; j < 4; j++) {
        float v0 = bf2f(hw[j] & 0xffffu) + bf2f(lw[j] & 0xffffu);
        float v1 = bf2f(hw[j] >> 16)     + bf2f(lw[j] >> 16);
        s += v0 * v0 + v1 * v1;
      }
    }
    mx = fmaxf(mx, s);
  }
#pragma unroll
  for (int o = 32; o; o >>= 1) mx = fmaxf(mx, __shfl_xor(mx, o));
  if ((tid & 63) == 0) tmp[tid >> 6] = mx;
  __syncthreads();
  if (tid == 0)
    Mk[bh] = sqrtf(fmaxf(fmaxf(tmp[0], tmp[1]), fmaxf(tmp[2], tmp[3])));
}

// k_attn (R19, unchanged): async-stage prefetch, exp2 softmax, reg-Q frags,
// fused softmax in QK C-dump, pair-exact PV MFMA, swizzled VA.

__global__ __launch_bounds__(512, 4) void k_attn(
    const float* __restrict__ Q, const unsigned short* __restrict__ KH,
    const unsigned short* __restrict__ KL, const unsigned int* __restrict__ VP,
    float* __restrict__ O, const float* __restrict__ Mk) {
  __shared__ unsigned short Qb[64][72];     // Q bf16 hi (x0.125*log2e)
  __shared__ unsigned short Ql[64][72];     // Q bf16 lo
  __shared__ unsigned short Kb[64][72];     // K bf16 hi
  __shared__ unsigned short Kl[64][72];     // K bf16 lo
  __shared__ unsigned int   VA[64][76];     // V^T pairs, col-swizzled
  __shared__ unsigned int   Pw[64][76];     // softmax weight pairs
  __shared__ float mbs[64];
  __shared__ float lsh[8][16];
  int i = blockIdx.x;
  int hb = (i & 7) | (((i >> 3) & 3) << 3);
  int p  = ((i >> 5) & 7) | (((i >> 8) & 1) << 3);
  int head = hb & 15, b = hb >> 4;
  int tid = threadIdx.x;
  int w = tid >> 6, lane = tid & 63;
  int quad = lane >> 2, dp = lane & 3;
  int d0 = dp << 4;
  int l15 = lane & 15, lhi = lane >> 4;
  int qh = w >> 2, ks = w & 3;
  long long bh_base = ((long long)b * SEQ) * H + head * HD;
  float mkv = Mk[b * 16 + head];

  int srow = tid >> 3;               // staging row 0..63
  int sd = (tid & 7) << 3;           // staging elem offset 0,8,..,56
  int vswz = (tid & 7) << 2;         // V^T staging column swizzle

  int qb = w >> 1;                   // wave's q-block (QK and PV epilogue)

  const float qscale = 0.125f * LOG2E;

  for (int ph = 0; ph < 2; ph++) {
    int g = ph ? (31 - p) : p;
    int qlo = g * 64;

    // stage Q tile as double-bf16 (x0.125*log2e), once per phase
    {
      const float* qg = Q + bh_base + (long long)(qlo + srow) * H + sd;
      float4 a = *(const float4*)qg;
      float4 c = *(const float4*)(qg + 4);
      uint4 phh, pll;
      phh.x = f2bf2hl(a.x * qscale, a.y * qscale, pll.x);
      phh.y = f2bf2hl(a.z * qscale, a.w * qscale, pll.y);
      phh.z = f2bf2hl(c.x * qscale, c.y * qscale, pll.z);
      phh.w = f2bf2hl(c.z * qscale, c.w * qscale, pll.w);
      *(uint4*)&Qb[srow][sd] = phh;
      *(uint4*)&Ql[srow][sd] = pll;
    }

    // fixed bound mb = log2e*0.125*|q|*max|k| into mbs[] (ks==0 waves)
    if (ks == 0) {
      int j0 = qh * 32 + quad * 2;
#pragma unroll
      for (int qq = 0; qq < 2; qq++) {
        int j = j0 + qq;
        const float4* qp_ = (const float4*)(Q + bh_base + (long long)(qlo + j) * H + d0);
        float ss = 0.f;
#pragma unroll
        for (int i2 = 0; i2 < 4; i2++) {
          float4 t = qp_[i2];
          ss += t.x * t.x + t.y * t.y + t.z * t.z + t.w * t.w;
        }
        ss += __shfl_xor(ss, 1);
        ss += __shfl_xor(ss, 2);
        if (dp == 0) mbs[j] = qscale * sqrtf(ss) * mkv;
      }
    }

    float lp[4] = {0.f, 0.f, 0.f, 0.f};
    f32x4 oacc[2];
#pragma unroll
    for (int fi = 0; fi < 2; fi++)
#pragma unroll
      for (int r = 0; r < 4; r++) oacc[fi][r] = 0.f;

    __syncthreads();   // Qb/Ql/mbs visible

    // hoist this lane's Q frags (tile-invariant) + row bounds to registers
    bf16x8 qah[2], qal[2];
#pragma unroll
    for (int ks2 = 0; ks2 < 2; ks2++) {
      qah[ks2] = *(const bf16x8*)&Qb[qb * 16 + l15][ks2 * 32 + lhi * 8];
      qal[ks2] = *(const bf16x8*)&Ql[qb * 16 + l15][ks2 * 32 + lhi * 8];
    }
    float mbr4[4];
#pragma unroll
    for (int r = 0; r < 4; r++) mbr4[r] = mbs[qb * 16 + lhi * 4 + r];

    // prefetch tile 0 K/V into registers (T14 async-stage)
    uint4 kh_r, kl_r, vp_r0, vp_r1;
    {
      long long idx = bh_base + (long long)(srow) * H + sd;
      kh_r = *(const uint4*)(KH + idx);
      kl_r = *(const uint4*)(KL + idx);
      const uint4* vg = (const uint4*)(VP + idx);
      vp_r0 = vg[0];
      vp_r1 = vg[1];
    }

    for (int t = 0; t <= g; t++) {
      // ---- staging phase: pure reg -> LDS writes
      {
        *(uint4*)&Kb[srow][sd] = kh_r;
        *(uint4*)&Kl[srow][sd] = kl_r;
        int col = srow ^ vswz;
        VA[sd + 0][col] = vp_r0.x;
        VA[sd + 1][col] = vp_r0.y;
        VA[sd + 2][col] = vp_r0.z;
        VA[sd + 3][col] = vp_r0.w;
        VA[sd + 4][col] = vp_r1.x;
        VA[sd + 5][col] = vp_r1.y;
        VA[sd + 6][col] = vp_r1.z;
        VA[sd + 7][col] = vp_r1.w;
      }
      __syncthreads();

      // issue next tile's loads now; latency hides under QK+PV
      if (t < g) {
        long long idx = bh_base + (long long)((t + 1) * 64 + srow) * H + sd;
        kh_r = *(const uint4*)(KH + idx);
        kl_r = *(const uint4*)(KL + idx);
        const uint4* vg = (const uint4*)(VP + idx);
        vp_r0 = vg[0];
        vp_r1 = vg[1];
      }

      // ---- QK^T MFMA (3-term double-bf16, reg A) + fused mask/exp2/pack -> Pw
      {
        bool dg = (t == g);
#pragma unroll
        for (int kb2 = 0; kb2 < 2; kb2++) {
          int kb = (w & 1) * 2 + kb2;
          f32x4 c = {0.f, 0.f, 0.f, 0.f};
          __builtin_amdgcn_s_setprio(1);
#pragma unroll
          for (int ks2 = 0; ks2 < 2; ks2++) {
            bf16x8 bh = *(const bf16x8*)&Kb[kb * 16 + l15][ks2 * 32 + lhi * 8];
            bf16x8 bl = *(const bf16x8*)&Kl[kb * 16 + l15][ks2 * 32 + lhi * 8];
            c = __builtin_amdgcn_mfma_f32_16x16x32_bf16(qal[ks2], bh, c, 0, 0, 0);
            c = __builtin_amdgcn_mfma_f32_16x16x32_bf16(qah[ks2], bl, c, 0, 0, 0);
            c = __builtin_amdgcn_mfma_f32_16x16x32_bf16(qah[ks2], bh, c, 0, 0, 0);
          }
          __builtin_amdgcn_s_setprio(0);
          int colc = kb * 16 + l15;
#pragma unroll
          for (int r = 0; r < 4; r++) {
            int row = qb * 16 + lhi * 4 + r;
            float wgt = (dg && colc > row) ? 0.f
                        : __builtin_amdgcn_exp2f(c[r] - mbr4[r]);
            lp[r] += wgt;
            Pw[row][colc] = fpair(wgt);
          }
        }
      }
      __syncthreads();

      // ---- PV MFMA: c4 outer (A-frag read once), fi inner (d-block)
      __builtin_amdgcn_s_setprio(1);
#pragma unroll
      for (int c4 = 0; c4 < 4; c4++) {
        bf16x8 af = *(const bf16x8*)&Pw[qb * 16 + l15][c4 * 16 + lhi * 4];
#pragma unroll
        for (int fi = 0; fi < 2; fi++) {
          int d4 = (w * 2 + fi) & 3;
          int row = d4 * 16 + l15;
          int rswz = ((row >> 3) & 7) << 2;
          union { uint4 q; unsigned int u[4]; bf16x8 v; } bb, bs;
          bb.q = *(const uint4*)&VA[row][(c4 * 16 + lhi * 4) ^ rswz];
          oacc[fi] = __builtin_amdgcn_mfma_f32_16x16x32_bf16(af, bb.v, oacc[fi], 0, 0, 0);
#pragma unroll
          for (int j = 0; j < 4; j++)
            bs.u[j] = ror16(bb.u[j]);
          oacc[fi] = __builtin_amdgcn_mfma_f32_16x16x32_bf16(af, bs.v, oacc[fi], 0, 0, 0);
        }
      }
      __builtin_amdgcn_s_setprio(0);
      __syncthreads();
    }

    // ---- l: reduce lp over the 16 l15 lanes (once per phase), publish per wave
#pragma unroll
    for (int r = 0; r < 4; r++) {
      lp[r] += __shfl_xor(lp[r], 1);
      lp[r] += __shfl_xor(lp[r], 2);
      lp[r] += __shfl_xor(lp[r], 4);
      lp[r] += __shfl_xor(lp[r], 8);
    }
    if (l15 == 0) {
#pragma unroll
      for (int r = 0; r < 4; r++) lsh[w][lhi * 4 + r] = lp[r];
    }
    __syncthreads();

    // ---- O epilogue: combine the two col-half waves' l, normalize, store
#pragma unroll
    for (int fi = 0; fi < 2; fi++) {
      int f = w * 2 + fi;
      int d4 = f & 3;
#pragma unroll
      for (int r = 0; r < 4; r++) {
        int idx = lhi * 4 + r;
        float lt = lsh[qb * 2][idx] + lsh[qb * 2 + 1][idx];
        float inv = 1.f / lt;
        int qrow = qb * 16 + idx;
        O[bh_base + (long long)(qlo + qrow) * H + d4 * 16 + l15] = oacc[fi][r] * inv;
      }
    }
    __syncthreads();                 // LDS reuse safe for next phase
  }
}

// ---------------- rmsnorm2 + router (argmax, fp64) + act_quant ----------------

__global__ __launch_bounds__(256) void k_rms2_router(
    const float* X2, const float* lnw, const float* rw,
    int8_t* xq, double* xsd, int* eidx) {
  __shared__ double tmp[4];
  __shared__ double xn[1024];
  __shared__ double logits[8];
  int t = blockIdx.x, tid = threadIdx.x;
  float4 xv = ((const float4*)(X2 + (long long)t * H))[tid];
  double x0 = xv.x, x1 = xv.y, x2 = xv.z, x3 = xv.w;
  double ss = x0 * x0 + x1 * x1 + x2 * x2 + x3 * x3;
  ss = bredd(ss, 0, tmp);
  double r = 1.0 / sqrt(ss * (1.0 / 1024.0) + 1e-5);
  float4 wv = ((const float4*)lnw)[tid];
  double n0 = x0 * r * wv.x, n1 = x1 * r * wv.y, n2 = x2 * r * wv.z, n3 = x3 * r * wv.w;
  xn[tid * 4 + 0] = n0; xn[tid * 4 + 1] = n1;
  xn[tid * 4 + 2] = n2; xn[tid * 4 + 3] = n3;
  double ma = fmax(fmax(fabs(n0), fabs(n1)), fmax(fabs(n2), fabs(n3)));
  ma = bredd(ma, 1, tmp);  // contains syncthreads -> xn visible
  double s = 127.0 / fmax(ma, 1e-5);
  ((int*)xq)[t * 256 + tid] = qpackd(n0, n1, n2, n3, s);
  if (tid == 0) xsd[t] = s;
  if (tid < 64) {
    int e = tid >> 3, i = tid & 7;
    const float* wr = rw + e * 1024;
    double p = 0.0;
    for (int h = i; h < 1024; h += 8) p += xn[h] * (double)wr[h];
    p += __shfl_xor(p, 1);
    p += __shfl_xor(p, 2);
    p += __shfl_xor(p, 4);
    if (i == 0) logits[e] = p;
  }
  __syncthreads();
  if (tid == 0) {
    double best = logits[0];
    int bi = 0;
    for (int e = 1; e < 8; e++)
      if (logits[e] > best) { best = logits[e]; bi = e; }
    eidx[t] = bi;
  }
}

// ---------------- MoE routing: group tokens by expert into padded 64-slot tiles ----
// meta[0] = ntile; meta[1+i] = expert of tile i. tokidx[slot] = token or -1 (pad).

__global__ __launch_bounds__(256) void k_route(const int* __restrict__ eidx,
                                               int* __restrict__ meta,
                                               int* __restrict__ tokidx) {
  __shared__ int cnt[8], pb[9], cur[8];
  int tid = threadIdx.x;
  if (tid < 8) cnt[tid] = 0;
  __syncthreads();
  for (int t = tid; t < NTOK; t += 256) atomicAdd(&cnt[eidx[t]], 1);
  __syncthreads();
  if (tid == 0) {
    pb[0] = 0;
    int nt = 0;
    for (int e = 0; e < 8; e++) {
      int tiles = (cnt[e] + 63) >> 6;
      for (int i = 0; i < tiles; i++) meta[1 + nt + i] = e;
      nt += tiles;
      pb[e + 1] = pb[e] + tiles * 64;
      cur[e] = pb[e];
    }
    meta[0] = nt;
  }
  __syncthreads();
  for (int s = tid; s < 4608; s += 256) tokidx[s] = -1;
  __syncthreads();
  for (int t = tid; t < NTOK; t += 256) {
    int e = eidx[t];
    int s = atomicAdd(&cur[e], 1);
    tokidx[s] = t;
  }
}

// ---------------- MoE gate+up GEMM via MFMA -> hh (fused relu(g)^2*u) ----------
// R20: global_load_lds staging; gathered X rows' token bases are loop-invariant
// per-lane registers (each lane's staging row fixed across the K-loop).

__global__ __launch_bounds__(256) void k_moe_gu(
    const int8_t* __restrict__ Xq, const double* __restrict__ xsd,
    const int8_t* __restrict__ qw, const double* __restrict__ wsd,
    const int* __restrict__ meta, const int* __restrict__ tokidx,
    float* __restrict__ hhbuf) {
  __shared__ i32x4 Xs[4][64];
  __shared__ i32x4 Wg[4][128];
  __shared__ i32x4 Wu[4][128];
  __shared__ double invg[64], invu[64];
  int tile = blockIdx.y;
  if (tile >= meta[0]) return;
  int e = meta[1 + tile];
  int n0 = blockIdx.x * 128;
  int s0 = tile * 64;
  int tid = threadIdx.x;
  int w = tid >> 6, lane = tid & 63;
  int lrow = lane & 31, lk = lane >> 5;
  const int8_t* Gg = qw + ((long long)(4 + e) << 20);
  const int8_t* Ug = qw + ((long long)(12 + e) << 20);
  i32x4* XsU = &Xs[0][0];
  i32x4* WgU = &Wg[0][0];
  i32x4* WuU = &Wu[0][0];
  int xv_ = w * 64 + lane;          // X unit 0..255
  int xrow_g = xv_ & 63, xkc_g = xv_ >> 6;
  int tokg = tokidx[s0 + xrow_g];
  if (tokg < 0) tokg = 0;
  const int8_t* xsrc = Xq + (long long)tokg * 1024 + xkc_g * 16;
  i32x16 accg[2], accu[2];
#pragma unroll
  for (int i = 0; i < 2; i++)
#pragma unroll
    for (int r = 0; r < 16; r++) { accg[i][r] = 0; accu[i][r] = 0; }

  for (int k0 = 0; k0 < 1024; k0 += 64) {
    gload16(xsrc + k0, XsU + w * 64);
#pragma unroll
    for (int j = 0; j < 2; j++) {
      int vb = w * 128 + j * 64;
      int v = vb + lane;
      int row = v & 127, kc = v >> 7;
      gload16(Gg + (long long)(n0 + row) * 1024 + k0 + kc * 16, WgU + vb);
      gload16(Ug + (long long)(n0 + row) * 1024 + k0 + kc * 16, WuU + vb);
    }
    __syncthreads();
#pragma unroll
    for (int ks = 0; ks < 2; ks++) {
      i32x4 a0 = Xs[ks * 2 + lk][lrow];
      i32x4 a1 = Xs[ks * 2 + lk][32 + lrow];
      i32x4 bg = Wg[ks * 2 + lk][w * 32 + lrow];
      i32x4 bu = Wu[ks * 2 + lk][w * 32 + lrow];
      accg[0] = mfma_i8(a0, bg, accg[0]);
      accg[1] = mfma_i8(a1, bg, accg[1]);
      accu[0] = mfma_i8(a0, bu, accu[0]);
      accu[1] = mfma_i8(a1, bu, accu[1]);
    }
    __syncthreads();
  }

  double swg = wsd[4 + e], swu = wsd[12 + e];
  if (tid < 64) {
    int tk = tokidx[s0 + tid];
    double xs = (tk < 0) ? 1.0 : xsd[tk];
    invg[tid] = 1.0 / (xs * swg);
    invu[tid] = 1.0 / (xs * swu);
  }
  __syncthreads();
  int n = n0 + w * 32 + lrow;
#pragma unroll
  for (int i = 0; i < 2; i++) {
#pragma unroll
    for (int r = 0; r < 16; r++) {
      int sl = i * 32 + (r & 3) + 8 * (r >> 2) + 4 * lk;
      int s = s0 + sl;
      int tok = tokidx[s];
      if (tok < 0) continue;
      double g = (double)accg[i][r] * invg[sl];
      double uu = (double)accu[i][r] * invu[sl];
      double rg = fmax(g, 0.0);
      hhbuf[(long long)s * DDIM + n] = (float)(rg * rg * uu);
    }
  }
}

// ---------------- act_quant over hh slot rows ----------------

__global__ __launch_bounds__(256) void k_hh_actq(
    const float* __restrict__ hhbuf, const int* __restrict__ meta,
    const int* __restrict__ tokidx, int8_t* __restrict__ hq,
    double* __restrict__ hsd) {
  __shared__ double tmp[4];
  int s = blockIdx.x;
  if (s >= meta[0] * 64) return;
  int tid = threadIdx.x;
  int tok = tokidx[s];
  if (tok < 0) {
    ((int*)hq)[s * 256 + tid] = 0;
    if (tid == 0) hsd[s] = 1.0;
    return;
  }
  float4 xv = ((const float4*)(hhbuf + (long long)s * DDIM))[tid];
  double x0 = xv.x, x1 = xv.y, x2 = xv.z, x3 = xv.w;
  double ma = fmax(fmax(fabs(x0), fabs(x1)), fmax(fabs(x2), fabs(x3)));
  ma = bredd(ma, 1, tmp);
  double sc = 127.0 / fmax(ma, 1e-5);
  ((int*)hq)[s * 256 + tid] = qpackd(x0, x1, x2, x3, sc);
  if (tid == 0) hsd[s] = sc;
}

// ---------------- MoE down GEMM via MFMA + residual -> out (scatter) ------------
// R20: global_load_lds staging (slot-contiguous X, no gather).

__global__ __launch_bounds__(256) void k_moe_down(
    const int8_t* __restrict__ hq, const double* __restrict__ hsd,
    const int8_t* __restrict__ qw, const double* __restrict__ wsd,
    const int* __restrict__ meta, const int* __restrict__ tokidx,
    const float* __restrict__ x2, float* __restrict__ out) {
  __shared__ i32x4 Xs[4][64];
  __shared__ i32x4 Ws[4][128];
  __shared__ double invd[64];
  int tile = blockIdx.y;
  if (tile >= meta[0]) return;
  int e = meta[1 + tile];
  int n0 = blockIdx.x * 128;
  int s0 = tile * 64;
  int tid = threadIdx.x;
  int w = tid >> 6, lane = tid & 63;
  int lrow = lane & 31, lk = lane >> 5;
  const int8_t* Wp = qw + ((long long)(20 + e) << 20);
  i32x4* XsU = &Xs[0][0];
  i32x4* WsU = &Ws[0][0];
  int xv_ = w * 64 + lane;
  int xrow_g = xv_ & 63, xkc_g = xv_ >> 6;
  const int8_t* xsrc = hq + (long long)(s0 + xrow_g) * 1024 + xkc_g * 16;
  i32x16 acc[2];
#pragma unroll
  for (int i = 0; i < 2; i++)
#pragma unroll
    for (int r = 0; r < 16; r++) acc[i][r] = 0;

  for (int k0 = 0; k0 < 1024; k0 += 64) {
    gload16(xsrc + k0, XsU + w * 64);
#pragma unroll
    for (int j = 0; j < 2; j++) {
      int vb = w * 128 + j * 64;
      int v = vb + lane;
      int row = v & 127, kc = v >> 7;
      gload16(Wp + (long long)(n0 + row) * 1024 + k0 + kc * 16, WsU + vb);
    }
    __syncthreads();
#pragma unroll
    for (int ks = 0; ks < 2; ks++) {
      i32x4 a0 = Xs[ks * 2 + lk][lrow];
      i32x4 a1 = Xs[ks * 2 + lk][32 + lrow];
      i32x4 b  = Ws[ks * 2 + lk][w * 32 + lrow];
      acc[0] = mfma_i8(a0, b, acc[0]);
      acc[1] = mfma_i8(a1, b, acc[1]);
    }
    __syncthreads();
  }

  double sw = wsd[20 + e];
  if (tid < 64) invd[tid] = 1.0 / (hsd[s0 + tid] * sw);
  __syncthreads();
  int n = n0 + w * 32 + lrow;
#pragma unroll
  for (int i = 0; i < 2; i++) {
#pragma unroll
    for (int r = 0; r < 16; r++) {
      int sl = i * 32 + (r & 3) + 8 * (r >> 2) + 4 * lk;
      int s = s0 + sl;
      int tok = tokidx[s];
      if (tok < 0) continue;
      out[(long long)tok * H + n] =
          (float)((double)x2[(long long)tok * H + n] + (double)acc[i][r] * invd[sl]);
    }
  }
}

// ---------------- launch ----------------
// ws layout (bytes):
//   0        partial double[28*1024] (224 KB)
//   229376   wsd double[28]
//   229600   xsd double[4096] (32 KB)
//   262368   eidx int[4096] (16 KB)
//   278752   Mk float[32]
//   278912   meta int[128]  (ntile + tile_e)
//   279424   tokidx int[4608] (18 KB)
//   297856   hsd double[4608] (36.9 KB)
//   1MB      qw int8: 28 x 1MB
//   29MB     xq int8 4MB
//   33MB     qbuf fp32 16MB (q -> attn out h); later hhbuf f32 [4544][1024] (18.6MB, 33..51.6)
//   49MB     Kh ushort 8MB (dead after attn); hq int8 @52..56.7 later (inside)
//   57MB     Kl ushort 8MB (dead after attn)
//   65MB     Vp uint32 16MB (dead after attn); x2 fp32 written here by o-proj
extern "C" void kernel_launch(void* const* d_in, const int* in_sizes, int n_in,
                              void* d_out, int out_size, void* d_ws, size_t ws_size,
                              hipStream_t stream) {
  const float* x   = (const float*)d_in[0];
  const float* qw_ = (const float*)d_in[1];
  const float* kw_ = (const float*)d_in[2];
  const float* vw_ = (const float*)d_in[3];
  const float* ow_ = (const float*)d_in[4];
  const float* ln1 = (const float*)d_in[5];
  const float* ln2 = (const float*)d_in[6];
  const float* rw  = (const float*)d_in[7];
  const float* gw  = (const float*)d_in[8];
  const float* uw  = (const float*)d_in[9];
  const float* dw  = (const float*)d_in[10];
  float* out = (float*)d_out;

  uint8_t* ws = (uint8_t*)d_ws;
  double* partial = (double*)ws;
  double* wsd    = (double*)(ws + 229376);
  double* xsd    = (double*)(ws + 229600);
  int*    eidx   = (int*)(ws + 262368);
  float*  Mk     = (float*)(ws + 278752);
  int*    meta   = (int*)(ws + 278912);
  int*    tokidx = (int*)(ws + 279424);
  double* hsd    = (double*)(ws + 297856);
  int8_t* qw     = (int8_t*)(ws + (1ull << 20));
  int8_t* xq     = (int8_t*)(ws + (29ull << 20));
  float*  qbuf   = (float*)(ws + (33ull << 20));
  float*  hhbuf  = (float*)(ws + (33ull << 20));   // aliases qbuf (dead by then)
  unsigned short* Kh = (unsigned short*)(ws + (49ull << 20));
  unsigned short* Kl = (unsigned short*)(ws + (57ull << 20));
  int8_t* hq     = (int8_t*)(ws + (52ull << 20));  // inside dead Kh region (post-attn)
  unsigned int* Vp = (unsigned int*)(ws + (65ull << 20));
  float*  vbuf   = (float*)(ws + (65ull << 20));   // x2 overwrites dead Vp post-attn

  // weight quantization (deterministic fp64 scales)
  k_absum<<<28 * 1024, 256, 0, stream>>>(qw_, kw_, vw_, ow_, gw, uw, dw, partial);
  k_wscale<<<28, 256, 0, stream>>>(partial, wsd);
  k_quantw<<<28 * 1024, 256, 0, stream>>>(qw_, kw_, vw_, ow_, gw, uw, dw, wsd, qw);

  // attention input: rmsnorm + act_quant
  k_rms1<<<NTOK, 256, 0, stream>>>(x, ln1, xq, xsd);
  // q/k/v projections fused; k/v written in attention-native packed formats
  k_gemm3<<<dim3(8, 32, 3), 256, 0, stream>>>(xq, xsd, qw, wsd, qbuf, Kh, Kl, Vp);
  // causal flash attention (async-stage prefetch, exp2 softmax, pair-exact PV)
  k_knorm<<<32, 256, 0, stream>>>(Kh, Kl, Mk);
  k_attn<<<dim3(512), 512, 0, stream>>>(qbuf, Kh, Kl, Vp, qbuf, Mk);
  // o projection with residual: x2 = x + bitlinear(h, o_w) -> vbuf (BM=64, 2/CU)
  k_actq<<<NTOK, 256, 0, stream>>>(qbuf, xq, xsd);
  k_gemm<<<dim3(8, 64), 256, 0, stream>>>(xq, xsd, qw + (3 << 20), wsd, 3, x, vbuf);
  // MoE: rmsnorm2 + router argmax + act_quant, then expert-gathered GEMMs
  k_rms2_router<<<NTOK, 256, 0, stream>>>(vbuf, ln2, rw, xq, xsd, eidx);
  k_route<<<1, 256, 0, stream>>>(eidx, meta, tokidx);
  k_moe_gu<<<dim3(8, 71), 256, 0, stream>>>(xq, xsd, qw, wsd, meta, tokidx, hhbuf);
  k_hh_actq<<<4544, 256, 0, stream>>>(hhbuf, meta, tokidx, hq, hsd);
  k_moe_down<<<dim3(8, 71), 256, 0, stream>>>(hq, hsd, qw, wsd, meta, tokidx, vbuf, out);
}

// Round 15
// 461.991 us; speedup vs baseline: 1.0578x; 1.0578x over previous
//
#include <hip/hip_runtime.h>
#include <stdint.h>
#include <math.h>

// Problem constants
#define NTOK 4096   // B*S
#define H    1024
#define NHEAD 16
#define HD   64
#define SEQ  2048
#define NE   8
#define DDIM 1024

typedef __attribute__((ext_vector_type(4)))  int i32x4;
typedef __attribute__((ext_vector_type(16))) int i32x16;
typedef __attribute__((ext_vector_type(8)))  short bf16x8;
typedef __attribute__((ext_vector_type(4)))  float f32x4;

#define LOG2E 1.4426950408889634f

// ---------------- helpers ----------------

__device__ __forceinline__ i32x16 mfma_i8(i32x4 a, i32x4 b, i32x16 c) {
  return __builtin_amdgcn_mfma_i32_32x32x32_i8(a, b, c, 0, 0, 0);
}

// float -> bf16 round-to-nearest-even (finite inputs)
__device__ __forceinline__ unsigned int f2bf(float f) {
  unsigned int u = __float_as_uint(f);
  return (u + 0x7fffu + ((u >> 16) & 1u)) >> 16;
}
__device__ __forceinline__ float bf2f(unsigned int b) {
  return __uint_as_float(b << 16);
}
// pack hi-parts of (a,b) into return, lo-parts (residual bf16) into lo
__device__ __forceinline__ unsigned int f2bf2hl(float a, float b, unsigned int& lo) {
  unsigned int ha = f2bf(a), hb = f2bf(b);
  lo = f2bf(a - bf2f(ha)) | (f2bf(b - bf2f(hb)) << 16);
  return ha | (hb << 16);
}
// pack double-bf16 pair of one float: low ushort = hi, high ushort = lo
__device__ __forceinline__ unsigned int fpair(float a) {
  unsigned int hi = f2bf(a);
  unsigned int lo = f2bf(a - bf2f(hi));
  return hi | (lo << 16);
}
__device__ __forceinline__ unsigned int ror16(unsigned int x) {
  return (x >> 16) | (x << 16);
}

// 256-thread block reduce (double). op=0 sum, op=1 max. tmp: __shared__ double[4]
__device__ __forceinline__ double bredd(double v, int op, double* tmp) {
#pragma unroll
  for (int o = 32; o; o >>= 1) {
    double w = __shfl_xor(v, o);
    v = op ? fmax(v, w) : v + w;
  }
  int wid = threadIdx.x >> 6;
  if ((threadIdx.x & 63) == 0) tmp[wid] = v;
  __syncthreads();
  double r = op ? fmax(fmax(tmp[0], tmp[1]), fmax(tmp[2], tmp[3]))
                : (tmp[0] + tmp[1] + tmp[2] + tmp[3]);
  __syncthreads();
  return r;
}

// quantize 4 doubles to packed int8 with double scale (round-half-even like jnp.round)
__device__ __forceinline__ int qpackd(double n0, double n1, double n2, double n3, double s) {
  int a = (int)fmin(fmax(rint(n0 * s), -128.0), 127.0);
  int b = (int)fmin(fmax(rint(n1 * s), -128.0), 127.0);
  int c = (int)fmin(fmax(rint(n2 * s), -128.0), 127.0);
  int d = (int)fmin(fmax(rint(n3 * s), -128.0), 127.0);
  return (a & 255) | ((b & 255) << 8) | ((c & 255) << 16) | ((d & 255) << 24);
}

// map flat tensor id (0..27, each 1M elems) -> source pointer
__device__ __forceinline__ const float* wsrc(int tensor,
    const float* qw_, const float* kw_, const float* vw_, const float* ow_,
    const float* gw_, const float* uw_, const float* dw_) {
  if (tensor < 4) return tensor == 0 ? qw_ : tensor == 1 ? kw_ : tensor == 2 ? vw_ : ow_;
  if (tensor < 12) return gw_ + ((long long)(tensor - 4) << 20);
  if (tensor < 20) return uw_ + ((long long)(tensor - 12) << 20);
  return dw_ + ((long long)(tensor - 20) << 20);
}

// ---------------- weight quantization (fp64 scale, deterministic) ----------------

__global__ __launch_bounds__(256) void k_absum(
    const float* qw_, const float* kw_, const float* vw_, const float* ow_,
    const float* gw_, const float* uw_, const float* dw_, double* partial) {
  __shared__ double tmp[4];
  int tensor = blockIdx.x >> 10;
  int j = ((blockIdx.x & 1023) << 10) + threadIdx.x * 4;
  const float* src = wsrc(tensor, qw_, kw_, vw_, ow_, gw_, uw_, dw_);
  float4 w = *(const float4*)(src + j);
  double v = fabs((double)w.x) + fabs((double)w.y) + fabs((double)w.z) + fabs((double)w.w);
  v = bredd(v, 0, tmp);
  if (threadIdx.x == 0) partial[blockIdx.x] = v;
}

__global__ __launch_bounds__(256) void k_wscale(const double* partial, double* wsd) {
  __shared__ double tmp[4];
  int tensor = blockIdx.x;
  const double* p = partial + (tensor << 10);
  int i = threadIdx.x * 4;
  double v = p[i] + p[i + 1] + p[i + 2] + p[i + 3];
  v = bredd(v, 0, tmp);
  if (threadIdx.x == 0) wsd[tensor] = 1.0 / fmax(v * (1.0 / 1048576.0), 1e-5);
}

__global__ __launch_bounds__(256) void k_quantw(
    const float* qw_, const float* kw_, const float* vw_, const float* ow_,
    const float* gw_, const float* uw_, const float* dw_,
    const double* wsd, int8_t* qw) {
  int tensor = blockIdx.x >> 10;
  int j = ((blockIdx.x & 1023) << 10) + threadIdx.x * 4;
  const float* src = wsrc(tensor, qw_, kw_, vw_, ow_, gw_, uw_, dw_);
  double s = wsd[tensor];
  float4 w = *(const float4*)(src + j);
  int a = (int)fmin(fmax(rint((double)w.x * s), -1.0), 1.0);
  int b = (int)fmin(fmax(rint((double)w.y * s), -1.0), 1.0);
  int c = (int)fmin(fmax(rint((double)w.z * s), -1.0), 1.0);
  int d = (int)fmin(fmax(rint((double)w.w * s), -1.0), 1.0);
  ((int*)qw)[(tensor << 18) + (j >> 2)] =
      (a & 255) | ((b & 255) << 8) | ((c & 255) << 16) | ((d & 255) << 24);
}

// ---------------- rmsnorm + act_quant (attention input), fp64 decisions ----------------

__global__ __launch_bounds__(256) void k_rms1(const float* X, const float* lnw,
                                              int8_t* xq, double* xsd) {
  __shared__ double tmp[4];
  int t = blockIdx.x, tid = threadIdx.x;
  float4 xv = ((const float4*)(X + (long long)t * H))[tid];
  double x0 = xv.x, x1 = xv.y, x2 = xv.z, x3 = xv.w;
  double ss = x0 * x0 + x1 * x1 + x2 * x2 + x3 * x3;
  ss = bredd(ss, 0, tmp);
  double r = 1.0 / sqrt(ss * (1.0 / 1024.0) + 1e-5);
  float4 wv = ((const float4*)lnw)[tid];
  double n0 = x0 * r * wv.x, n1 = x1 * r * wv.y, n2 = x2 * r * wv.z, n3 = x3 * r * wv.w;
  double ma = fmax(fmax(fabs(n0), fabs(n1)), fmax(fabs(n2), fabs(n3)));
  ma = bredd(ma, 1, tmp);
  double s = 127.0 / fmax(ma, 1e-5);
  ((int*)xq)[t * 256 + tid] = qpackd(n0, n1, n2, n3, s);
  if (tid == 0) xsd[t] = s;
}

// act_quant only (rows of 1024 floats), fp64 decisions
__global__ __launch_bounds__(256) void k_actq(const float* X, int8_t* xq, double* xsd) {
  __shared__ double tmp[4];
  int t = blockIdx.x, tid = threadIdx.x;
  float4 xv = ((const float4*)(X + (long long)t * H))[tid];
  double x0 = xv.x, x1 = xv.y, x2 = xv.z, x3 = xv.w;
  double ma = fmax(fmax(fabs(x0), fabs(x1)), fmax(fabs(x2), fabs(x3)));
  ma = bredd(ma, 1, tmp);
  double s = 127.0 / fmax(ma, 1e-5);
  ((int*)xq)[t * 256 + tid] = qpackd(x0, x1, x2, x3, s);
  if (tid == 0) xsd[t] = s;
}

// ---------------- int8 GEMM via MFMA (o-proj): out = res + acc/(xs*sw) ----------
// BM=64 BN=128 BK=64 -> 512 blocks = 2/CU. Reg-staged (R20's global_load_lds
// regressed: it blocks the compiler's cross-iteration load pipelining since the
// LDS dest is live; reg staging lets next-iter loads issue under current MFMAs).

__global__ __launch_bounds__(256) void k_gemm(
    const int8_t* __restrict__ Xq, const double* __restrict__ xsd,
    const int8_t* __restrict__ W, const double* __restrict__ wsd, int widx,
    const float* __restrict__ residual, float* __restrict__ out) {
  __shared__ i32x4 Xs[4][64];
  __shared__ i32x4 Ws[4][128];
  __shared__ double invs[64];
  int tid = threadIdx.x;
  int t0 = blockIdx.y * 64, n0 = blockIdx.x * 128;
  int w = tid >> 6, lane = tid & 63;
  int lrow = lane & 31, lk = lane >> 5;
  int xrow = tid >> 2, xkc = tid & 3;
  i32x16 acc[2];
#pragma unroll
  for (int i = 0; i < 2; i++)
#pragma unroll
    for (int r = 0; r < 16; r++) acc[i][r] = 0;

  for (int k0 = 0; k0 < 1024; k0 += 64) {
    Xs[xkc][xrow] = *(const i32x4*)(Xq + (long long)(t0 + xrow) * 1024 + k0 + xkc * 16);
#pragma unroll
    for (int i = 0; i < 2; i++) {
      int u = tid * 2 + i;
      int row = u >> 2, kc = u & 3;
      Ws[kc][row] = *(const i32x4*)(W + (long long)(n0 + row) * 1024 + k0 + kc * 16);
    }
    __syncthreads();
#pragma unroll
    for (int ks = 0; ks < 2; ks++) {
      i32x4 a0 = Xs[ks * 2 + lk][lrow];
      i32x4 a1 = Xs[ks * 2 + lk][32 + lrow];
      i32x4 b  = Ws[ks * 2 + lk][w * 32 + lrow];
      acc[0] = mfma_i8(a0, b, acc[0]);
      acc[1] = mfma_i8(a1, b, acc[1]);
    }
    __syncthreads();
  }

  double sw = wsd[widx];
  if (tid < 64) invs[tid] = 1.0 / (xsd[t0 + tid] * sw);
  __syncthreads();
  int n = n0 + w * 32 + lrow;
#pragma unroll
  for (int i = 0; i < 2; i++) {
#pragma unroll
    for (int r = 0; r < 16; r++) {
      int rl = i * 32 + (r & 3) + 8 * (r >> 2) + 4 * lk;
      int trow = t0 + rl;
      double v = (double)acc[i][r] * invs[rl];
      if (residual) v += (double)residual[(long long)trow * H + n];
      out[(long long)trow * H + n] = (float)v;
    }
  }
}

// k_gemm3: fused q/k/v projections writing ATTENTION-NATIVE formats:
//   z==0 (q): fp32 qbuf; z==1 (k): split double-bf16 planes Kh/Kl;
//   z==2 (v): interleaved pair words Vp (fpair). Reg-staged.

__global__ __launch_bounds__(256) void k_gemm3(
    const int8_t* __restrict__ Xq, const double* __restrict__ xsd,
    const int8_t* __restrict__ qw, const double* __restrict__ wsd,
    float* __restrict__ outq, unsigned short* __restrict__ Kh,
    unsigned short* __restrict__ Kl, unsigned int* __restrict__ Vp) {
  __shared__ i32x4 Xs[4][128];
  __shared__ i32x4 Ws[4][128];
  __shared__ double invs[128];
  int z = blockIdx.z;
  const int8_t* W = qw + ((long long)z << 20);
  int tid = threadIdx.x;
  int t0 = blockIdx.y * 128, n0 = blockIdx.x * 128;
  int w = tid >> 6, lane = tid & 63;
  int wm = w >> 1, wn = w & 1;
  int lrow = lane & 31, lk = lane >> 5;
  i32x16 acc[2][2];
#pragma unroll
  for (int i = 0; i < 2; i++)
#pragma unroll
    for (int j = 0; j < 2; j++)
#pragma unroll
      for (int r = 0; r < 16; r++) acc[i][j][r] = 0;

  for (int k0 = 0; k0 < 1024; k0 += 64) {
#pragma unroll
    for (int i = 0; i < 2; i++) {
      int u = tid * 2 + i;
      int row = u >> 2, kc = u & 3;
      Xs[kc][row] = *(const i32x4*)(Xq + (long long)(t0 + row) * 1024 + k0 + kc * 16);
      Ws[kc][row] = *(const i32x4*)(W  + (long long)(n0 + row) * 1024 + k0 + kc * 16);
    }
    __syncthreads();
#pragma unroll
    for (int ks = 0; ks < 2; ks++) {
      i32x4 a0 = Xs[ks * 2 + lk][wm * 64 + lrow];
      i32x4 a1 = Xs[ks * 2 + lk][wm * 64 + 32 + lrow];
      i32x4 b0 = Ws[ks * 2 + lk][wn * 64 + lrow];
      i32x4 b1 = Ws[ks * 2 + lk][wn * 64 + 32 + lrow];
      acc[0][0] = mfma_i8(a0, b0, acc[0][0]);
      acc[0][1] = mfma_i8(a0, b1, acc[0][1]);
      acc[1][0] = mfma_i8(a1, b0, acc[1][0]);
      acc[1][1] = mfma_i8(a1, b1, acc[1][1]);
    }
    __syncthreads();
  }

  double sw = wsd[z];
  if (tid < 128) invs[tid] = 1.0 / (xsd[t0 + tid] * sw);
  __syncthreads();
#pragma unroll
  for (int i = 0; i < 2; i++) {
#pragma unroll
    for (int r = 0; r < 16; r++) {
      int rloc = wm * 64 + i * 32 + (r & 3) + 8 * (r >> 2) + 4 * lk;
      long long base = (long long)(t0 + rloc) * H;
      double inv = invs[rloc];
#pragma unroll
      for (int j = 0; j < 2; j++) {
        int n = n0 + wn * 64 + j * 32 + lrow;
        float vf = (float)((double)acc[i][j][r] * inv);
        long long idx = base + n;
        if (z == 0) {
          outq[idx] = vf;
        } else if (z == 1) {
          unsigned int h = f2bf(vf);
          unsigned int l = f2bf(vf - bf2f(h));
          Kh[idx] = (unsigned short)h;
          Kl[idx] = (unsigned short)l;
        } else {
          Vp[idx] = fpair(vf);
        }
      }
    }
  }
}

// ---------------- attention ----------------
// k_knorm: per-(b,head) max key L2-norm from packed Kh/Kl (reconstruct h+l).

__global__ __launch_bounds__(256) void k_knorm(const unsigned short* __restrict__ Kh,
                                               const unsigned short* __restrict__ Kl,
                                               float* __restrict__ Mk) {
  __shared__ float tmp[4];
  int bh = blockIdx.x;          // b*16 + head
  int b = bh >> 4, head = bh & 15;
  int tid = threadIdx.x;
  float mx = 0.f;
  for (int key = tid; key < SEQ; key += 256) {
    long long base = ((long long)(b * SEQ + key)) * H + head * HD;
    const uint4* hq4 = (const uint4*)(Kh + base);
    const uint4* lq4 = (const uint4*)(Kl + base);
    float s = 0.f;
#pragma unroll
    for (int i = 0; i < 8; i++) {         // 8 x (8 ushorts) = 64 elems
      uint4 hu = hq4[i], lu = lq4[i];
      const unsigned int hw[4] = {hu.x, hu.y, hu.z, hu.w};
      const unsigned int lw[4] = {lu.x, lu.y, lu.z, lu.w};
#pragma unroll
      for (int j = 0; j < 4; j++) {
        float v0 = bf2f(hw[j] & 0xffffu) + bf2f(lw[j] & 0xffffu);
        float v1 = bf2f(hw[j] >> 16)     + bf2f(lw[j] >> 16);
        s += v0 * v0 + v1 * v1;
      }
    }
    mx = fmaxf(mx, s);
  }
#pragma unroll
  for (int o = 32; o; o >>= 1) mx = fmaxf(mx, __shfl_xor(mx, o));
  if ((tid & 63) == 0) tmp[tid >> 6] = mx;
  __syncthreads();
  if (tid == 0)
    Mk[bh] = sqrtf(fmaxf(fmaxf(tmp[0], tmp[1]), fmaxf(tmp[2], tmp[3])));
}

// k_attn (R19): async-stage prefetch, exp2 softmax, reg-Q frags,
// fused softmax in QK C-dump, pair-exact PV MFMA, swizzled VA.

__global__ __launch_bounds__(512, 4) void k_attn(
    const float* __restrict__ Q, const unsigned short* __restrict__ KH,
    const unsigned short* __restrict__ KL, const unsigned int* __restrict__ VP,
    float* __restrict__ O, const float* __restrict__ Mk) {
  __shared__ unsigned short Qb[64][72];     // Q bf16 hi (x0.125*log2e)
  __shared__ unsigned short Ql[64][72];     // Q bf16 lo
  __shared__ unsigned short Kb[64][72];     // K bf16 hi
  __shared__ unsigned short Kl[64][72];     // K bf16 lo
  __shared__ unsigned int   VA[64][76];     // V^T pairs, col-swizzled
  __shared__ unsigned int   Pw[64][76];     // softmax weight pairs
  __shared__ float mbs[64];
  __shared__ float lsh[8][16];
  int i = blockIdx.x;
  int hb = (i & 7) | (((i >> 3) & 3) << 3);
  int p  = ((i >> 5) & 7) | (((i >> 8) & 1) << 3);
  int head = hb & 15, b = hb >> 4;
  int tid = threadIdx.x;
  int w = tid >> 6, lane = tid & 63;
  int quad = lane >> 2, dp = lane & 3;
  int d0 = dp << 4;
  int l15 = lane & 15, lhi = lane >> 4;
  int qh = w >> 2, ks = w & 3;
  long long bh_base = ((long long)b * SEQ) * H + head * HD;
  float mkv = Mk[b * 16 + head];

  int srow = tid >> 3;               // staging row 0..63
  int sd = (tid & 7) << 3;           // staging elem offset 0,8,..,56
  int vswz = (tid & 7) << 2;         // V^T staging column swizzle

  int qb = w >> 1;                   // wave's q-block (QK and PV epilogue)

  const float qscale = 0.125f * LOG2E;

  for (int ph = 0; ph < 2; ph++) {
    int g = ph ? (31 - p) : p;
    int qlo = g * 64;

    // stage Q tile as double-bf16 (x0.125*log2e), once per phase
    {
      const float* qg = Q + bh_base + (long long)(qlo + srow) * H + sd;
      float4 a = *(const float4*)qg;
      float4 c = *(const float4*)(qg + 4);
      uint4 phh, pll;
      phh.x = f2bf2hl(a.x * qscale, a.y * qscale, pll.x);
      phh.y = f2bf2hl(a.z * qscale, a.w * qscale, pll.y);
      phh.z = f2bf2hl(c.x * qscale, c.y * qscale, pll.z);
      phh.w = f2bf2hl(c.z * qscale, c.w * qscale, pll.w);
      *(uint4*)&Qb[srow][sd] = phh;
      *(uint4*)&Ql[srow][sd] = pll;
    }

    // fixed bound mb = log2e*0.125*|q|*max|k| into mbs[] (ks==0 waves)
    if (ks == 0) {
      int j0 = qh * 32 + quad * 2;
#pragma unroll
      for (int qq = 0; qq < 2; qq++) {
        int j = j0 + qq;
        const float4* qp_ = (const float4*)(Q + bh_base + (long long)(qlo + j) * H + d0);
        float ss = 0.f;
#pragma unroll
        for (int i2 = 0; i2 < 4; i2++) {
          float4 t = qp_[i2];
          ss += t.x * t.x + t.y * t.y + t.z * t.z + t.w * t.w;
        }
        ss += __shfl_xor(ss, 1);
        ss += __shfl_xor(ss, 2);
        if (dp == 0) mbs[j] = qscale * sqrtf(ss) * mkv;
      }
    }

    float lp[4] = {0.f, 0.f, 0.f, 0.f};
    f32x4 oacc[2];
#pragma unroll
    for (int fi = 0; fi < 2; fi++)
#pragma unroll
      for (int r = 0; r < 4; r++) oacc[fi][r] = 0.f;

    __syncthreads();   // Qb/Ql/mbs visible

    // hoist this lane's Q frags (tile-invariant) + row bounds to registers
    bf16x8 qah[2], qal[2];
#pragma unroll
    for (int ks2 = 0; ks2 < 2; ks2++) {
      qah[ks2] = *(const bf16x8*)&Qb[qb * 16 + l15][ks2 * 32 + lhi * 8];
      qal[ks2] = *(const bf16x8*)&Ql[qb * 16 + l15][ks2 * 32 + lhi * 8];
    }
    float mbr4[4];
#pragma unroll
    for (int r = 0; r < 4; r++) mbr4[r] = mbs[qb * 16 + lhi * 4 + r];

    // prefetch tile 0 K/V into registers (T14 async-stage)
    uint4 kh_r, kl_r, vp_r0, vp_r1;
    {
      long long idx = bh_base + (long long)(srow) * H + sd;
      kh_r = *(const uint4*)(KH + idx);
      kl_r = *(const uint4*)(KL + idx);
      const uint4* vg = (const uint4*)(VP + idx);
      vp_r0 = vg[0];
      vp_r1 = vg[1];
    }

    for (int t = 0; t <= g; t++) {
      // ---- staging phase: pure reg -> LDS writes
      {
        *(uint4*)&Kb[srow][sd] = kh_r;
        *(uint4*)&Kl[srow][sd] = kl_r;
        int col = srow ^ vswz;
        VA[sd + 0][col] = vp_r0.x;
        VA[sd + 1][col] = vp_r0.y;
        VA[sd + 2][col] = vp_r0.z;
        VA[sd + 3][col] = vp_r0.w;
        VA[sd + 4][col] = vp_r1.x;
        VA[sd + 5][col] = vp_r1.y;
        VA[sd + 6][col] = vp_r1.z;
        VA[sd + 7][col] = vp_r1.w;
      }
      __syncthreads();

      // issue next tile's loads now; latency hides under QK+PV
      if (t < g) {
        long long idx = bh_base + (long long)((t + 1) * 64 + srow) * H + sd;
        kh_r = *(const uint4*)(KH + idx);
        kl_r = *(const uint4*)(KL + idx);
        const uint4* vg = (const uint4*)(VP + idx);
        vp_r0 = vg[0];
        vp_r1 = vg[1];
      }

      // ---- QK^T MFMA (3-term double-bf16, reg A) + fused mask/exp2/pack -> Pw
      {
        bool dg = (t == g);
#pragma unroll
        for (int kb2 = 0; kb2 < 2; kb2++) {
          int kb = (w & 1) * 2 + kb2;
          f32x4 c = {0.f, 0.f, 0.f, 0.f};
          __builtin_amdgcn_s_setprio(1);
#pragma unroll
          for (int ks2 = 0; ks2 < 2; ks2++) {
            bf16x8 bh = *(const bf16x8*)&Kb[kb * 16 + l15][ks2 * 32 + lhi * 8];
            bf16x8 bl = *(const bf16x8*)&Kl[kb * 16 + l15][ks2 * 32 + lhi * 8];
            c = __builtin_amdgcn_mfma_f32_16x16x32_bf16(qal[ks2], bh, c, 0, 0, 0);
            c = __builtin_amdgcn_mfma_f32_16x16x32_bf16(qah[ks2], bl, c, 0, 0, 0);
            c = __builtin_amdgcn_mfma_f32_16x16x32_bf16(qah[ks2], bh, c, 0, 0, 0);
          }
          __builtin_amdgcn_s_setprio(0);
          int colc = kb * 16 + l15;
#pragma unroll
          for (int r = 0; r < 4; r++) {
            int row = qb * 16 + lhi * 4 + r;
            float wgt = (dg && colc > row) ? 0.f
                        : __builtin_amdgcn_exp2f(c[r] - mbr4[r]);
            lp[r] += wgt;
            Pw[row][colc] = fpair(wgt);
          }
        }
      }
      __syncthreads();

      // ---- PV MFMA: c4 outer (A-frag read once), fi inner (d-block)
      __builtin_amdgcn_s_setprio(1);
#pragma unroll
      for (int c4 = 0; c4 < 4; c4++) {
        bf16x8 af = *(const bf16x8*)&Pw[qb * 16 + l15][c4 * 16 + lhi * 4];
#pragma unroll
        for (int fi = 0; fi < 2; fi++) {
          int d4 = (w * 2 + fi) & 3;
          int row = d4 * 16 + l15;
          int rswz = ((row >> 3) & 7) << 2;
          union { uint4 q; unsigned int u[4]; bf16x8 v; } bb, bs;
          bb.q = *(const uint4*)&VA[row][(c4 * 16 + lhi * 4) ^ rswz];
          oacc[fi] = __builtin_amdgcn_mfma_f32_16x16x32_bf16(af, bb.v, oacc[fi], 0, 0, 0);
#pragma unroll
          for (int j = 0; j < 4; j++)
            bs.u[j] = ror16(bb.u[j]);
          oacc[fi] = __builtin_amdgcn_mfma_f32_16x16x32_bf16(af, bs.v, oacc[fi], 0, 0, 0);
        }
      }
      __builtin_amdgcn_s_setprio(0);
      __syncthreads();
    }

    // ---- l: reduce lp over the 16 l15 lanes (once per phase), publish per wave
#pragma unroll
    for (int r = 0; r < 4; r++) {
      lp[r] += __shfl_xor(lp[r], 1);
      lp[r] += __shfl_xor(lp[r], 2);
      lp[r] += __shfl_xor(lp[r], 4);
      lp[r] += __shfl_xor(lp[r], 8);
    }
    if (l15 == 0) {
#pragma unroll
      for (int r = 0; r < 4; r++) lsh[w][lhi * 4 + r] = lp[r];
    }
    __syncthreads();

    // ---- O epilogue: combine the two col-half waves' l, normalize, store
#pragma unroll
    for (int fi = 0; fi < 2; fi++) {
      int f = w * 2 + fi;
      int d4 = f & 3;
#pragma unroll
      for (int r = 0; r < 4; r++) {
        int idx = lhi * 4 + r;
        float lt = lsh[qb * 2][idx] + lsh[qb * 2 + 1][idx];
        float inv = 1.f / lt;
        int qrow = qb * 16 + idx;
        O[bh_base + (long long)(qlo + qrow) * H + d4 * 16 + l15] = oacc[fi][r] * inv;
      }
    }
    __syncthreads();                 // LDS reuse safe for next phase
  }
}

// ---------------- rmsnorm2 + router (argmax, fp64) + act_quant ----------------

__global__ __launch_bounds__(256) void k_rms2_router(
    const float* X2, const float* lnw, const float* rw,
    int8_t* xq, double* xsd, int* eidx) {
  __shared__ double tmp[4];
  __shared__ double xn[1024];
  __shared__ double logits[8];
  int t = blockIdx.x, tid = threadIdx.x;
  float4 xv = ((const float4*)(X2 + (long long)t * H))[tid];
  double x0 = xv.x, x1 = xv.y, x2 = xv.z, x3 = xv.w;
  double ss = x0 * x0 + x1 * x1 + x2 * x2 + x3 * x3;
  ss = bredd(ss, 0, tmp);
  double r = 1.0 / sqrt(ss * (1.0 / 1024.0) + 1e-5);
  float4 wv = ((const float4*)lnw)[tid];
  double n0 = x0 * r * wv.x, n1 = x1 * r * wv.y, n2 = x2 * r * wv.z, n3 = x3 * r * wv.w;
  xn[tid * 4 + 0] = n0; xn[tid * 4 + 1] = n1;
  xn[tid * 4 + 2] = n2; xn[tid * 4 + 3] = n3;
  double ma = fmax(fmax(fabs(n0), fabs(n1)), fmax(fabs(n2), fabs(n3)));
  ma = bredd(ma, 1, tmp);  // contains syncthreads -> xn visible
  double s = 127.0 / fmax(ma, 1e-5);
  ((int*)xq)[t * 256 + tid] = qpackd(n0, n1, n2, n3, s);
  if (tid == 0) xsd[t] = s;
  if (tid < 64) {
    int e = tid >> 3, i = tid & 7;
    const float* wr = rw + e * 1024;
    double p = 0.0;
    for (int h = i; h < 1024; h += 8) p += xn[h] * (double)wr[h];
    p += __shfl_xor(p, 1);
    p += __shfl_xor(p, 2);
    p += __shfl_xor(p, 4);
    if (i == 0) logits[e] = p;
  }
  __syncthreads();
  if (tid == 0) {
    double best = logits[0];
    int bi = 0;
    for (int e = 1; e < 8; e++)
      if (logits[e] > best) { best = logits[e]; bi = e; }
    eidx[t] = bi;
  }
}

// ---------------- MoE routing: group tokens by expert into padded 64-slot tiles ----
// meta[0] = ntile; meta[1+i] = expert of tile i. tokidx[slot] = token or -1 (pad).

__global__ __launch_bounds__(256) void k_route(const int* __restrict__ eidx,
                                               int* __restrict__ meta,
                                               int* __restrict__ tokidx) {
  __shared__ int cnt[8], pb[9], cur[8];
  int tid = threadIdx.x;
  if (tid < 8) cnt[tid] = 0;
  __syncthreads();
  for (int t = tid; t < NTOK; t += 256) atomicAdd(&cnt[eidx[t]], 1);
  __syncthreads();
  if (tid == 0) {
    pb[0] = 0;
    int nt = 0;
    for (int e = 0; e < 8; e++) {
      int tiles = (cnt[e] + 63) >> 6;
      for (int i = 0; i < tiles; i++) meta[1 + nt + i] = e;
      nt += tiles;
      pb[e + 1] = pb[e] + tiles * 64;
      cur[e] = pb[e];
    }
    meta[0] = nt;
  }
  __syncthreads();
  for (int s = tid; s < 4608; s += 256) tokidx[s] = -1;
  __syncthreads();
  for (int t = tid; t < NTOK; t += 256) {
    int e = eidx[t];
    int s = atomicAdd(&cur[e], 1);
    tokidx[s] = t;
  }
}

// ---------------- MoE gate+up GEMM via MFMA -> hh (fused relu(g)^2*u) ----------

__global__ __launch_bounds__(256) void k_moe_gu(
    const int8_t* __restrict__ Xq, const double* __restrict__ xsd,
    const int8_t* __restrict__ qw, const double* __restrict__ wsd,
    const int* __restrict__ meta, const int* __restrict__ tokidx,
    float* __restrict__ hhbuf) {
  __shared__ i32x4 Xs[4][64];
  __shared__ i32x4 Wg[4][128];
  __shared__ i32x4 Wu[4][128];
  __shared__ double invg[64], invu[64];
  int tile = blockIdx.y;
  if (tile >= meta[0]) return;
  int e = meta[1 + tile];
  int n0 = blockIdx.x * 128;
  int s0 = tile * 64;
  int tid = threadIdx.x;
  int w = tid >> 6, lane = tid & 63;
  int lrow = lane & 31, lk = lane >> 5;
  const int8_t* Gg = qw + ((long long)(4 + e) << 20);
  const int8_t* Ug = qw + ((long long)(12 + e) << 20);
  int xrow = tid >> 2, xkc = tid & 3;
  int tokr = tokidx[s0 + xrow];
  if (tokr < 0) tokr = 0;
  i32x16 accg[2], accu[2];
#pragma unroll
  for (int i = 0; i < 2; i++)
#pragma unroll
    for (int r = 0; r < 16; r++) { accg[i][r] = 0; accu[i][r] = 0; }

  for (int k0 = 0; k0 < 1024; k0 += 64) {
    Xs[xkc][xrow] = *(const i32x4*)(Xq + (long long)tokr * 1024 + k0 + xkc * 16);
#pragma unroll
    for (int i = 0; i < 2; i++) {
      int u = tid * 2 + i;                 // 0..511
      int row = u >> 2, kc = u & 3;
      Wg[kc][row] = *(const i32x4*)(Gg + (long long)(n0 + row) * 1024 + k0 + kc * 16);
      Wu[kc][row] = *(const i32x4*)(Ug + (long long)(n0 + row) * 1024 + k0 + kc * 16);
    }
    __syncthreads();
#pragma unroll
    for (int ks = 0; ks < 2; ks++) {
      i32x4 a0 = Xs[ks * 2 + lk][lrow];
      i32x4 a1 = Xs[ks * 2 + lk][32 + lrow];
      i32x4 bg = Wg[ks * 2 + lk][w * 32 + lrow];
      i32x4 bu = Wu[ks * 2 + lk][w * 32 + lrow];
      accg[0] = mfma_i8(a0, bg, accg[0]);
      accg[1] = mfma_i8(a1, bg, accg[1]);
      accu[0] = mfma_i8(a0, bu, accu[0]);
      accu[1] = mfma_i8(a1, bu, accu[1]);
    }
    __syncthreads();
  }

  double swg = wsd[4 + e], swu = wsd[12 + e];
  if (tid < 64) {
    int tk = tokidx[s0 + tid];
    double xs = (tk < 0) ? 1.0 : xsd[tk];
    invg[tid] = 1.0 / (xs * swg);
    invu[tid] = 1.0 / (xs * swu);
  }
  __syncthreads();
  int n = n0 + w * 32 + lrow;
#pragma unroll
  for (int i = 0; i < 2; i++) {
#pragma unroll
    for (int r = 0; r < 16; r++) {
      int sl = i * 32 + (r & 3) + 8 * (r >> 2) + 4 * lk;
      int s = s0 + sl;
      int tok = tokidx[s];
      if (tok < 0) continue;
      double g = (double)accg[i][r] * invg[sl];
      double uu = (double)accu[i][r] * invu[sl];
      double rg = fmax(g, 0.0);
      hhbuf[(long long)s * DDIM + n] = (float)(rg * rg * uu);
    }
  }
}

// ---------------- act_quant over hh slot rows ----------------

__global__ __launch_bounds__(256) void k_hh_actq(
    const float* __restrict__ hhbuf, const int* __restrict__ meta,
    const int* __restrict__ tokidx, int8_t* __restrict__ hq,
    double* __restrict__ hsd) {
  __shared__ double tmp[4];
  int s = blockIdx.x;
  if (s >= meta[0] * 64) return;
  int tid = threadIdx.x;
  int tok = tokidx[s];
  if (tok < 0) {
    ((int*)hq)[s * 256 + tid] = 0;
    if (tid == 0) hsd[s] = 1.0;
    return;
  }
  float4 xv = ((const float4*)(hhbuf + (long long)s * DDIM))[tid];
  double x0 = xv.x, x1 = xv.y, x2 = xv.z, x3 = xv.w;
  double ma = fmax(fmax(fabs(x0), fabs(x1)), fmax(fabs(x2), fabs(x3)));
  ma = bredd(ma, 1, tmp);
  double sc = 127.0 / fmax(ma, 1e-5);
  ((int*)hq)[s * 256 + tid] = qpackd(x0, x1, x2, x3, sc);
  if (tid == 0) hsd[s] = sc;
}

// ---------------- MoE down GEMM via MFMA + residual -> out (scatter) ------------

__global__ __launch_bounds__(256) void k_moe_down(
    const int8_t* __restrict__ hq, const double* __restrict__ hsd,
    const int8_t* __restrict__ qw, const double* __restrict__ wsd,
    const int* __restrict__ meta, const int* __restrict__ tokidx,
    const float* __restrict__ x2, float* __restrict__ out) {
  __shared__ i32x4 Xs[4][64];
  __shared__ i32x4 Ws[4][128];
  __shared__ double invd[64];
  int tile = blockIdx.y;
  if (tile >= meta[0]) return;
  int e = meta[1 + tile];
  int n0 = blockIdx.x * 128;
  int s0 = tile * 64;
  int tid = threadIdx.x;
  int w = tid >> 6, lane = tid & 63;
  int lrow = lane & 31, lk = lane >> 5;
  const int8_t* Wp = qw + ((long long)(20 + e) << 20);
  int xrow = tid >> 2, xkc = tid & 3;
  i32x16 acc[2];
#pragma unroll
  for (int i = 0; i < 2; i++)
#pragma unroll
    for (int r = 0; r < 16; r++) acc[i][r] = 0;

  for (int k0 = 0; k0 < 1024; k0 += 64) {
    Xs[xkc][xrow] = *(const i32x4*)(hq + (long long)(s0 + xrow) * 1024 + k0 + xkc * 16);
#pragma unroll
    for (int i = 0; i < 2; i++) {
      int u = tid * 2 + i;
      int row = u >> 2, kc = u & 3;
      Ws[kc][row] = *(const i32x4*)(Wp + (long long)(n0 + row) * 1024 + k0 + kc * 16);
    }
    __syncthreads();
#pragma unroll
    for (int ks = 0; ks < 2; ks++) {
      i32x4 a0 = Xs[ks * 2 + lk][lrow];
      i32x4 a1 = Xs[ks * 2 + lk][32 + lrow];
      i32x4 b  = Ws[ks * 2 + lk][w * 32 + lrow];
      acc[0] = mfma_i8(a0, b, acc[0]);
      acc[1] = mfma_i8(a1, b, acc[1]);
    }
    __syncthreads();
  }

  double sw = wsd[20 + e];
  if (tid < 64) invd[tid] = 1.0 / (hsd[s0 + tid] * sw);
  __syncthreads();
  int n = n0 + w * 32 + lrow;
#pragma unroll
  for (int i = 0; i < 2; i++) {
#pragma unroll
    for (int r = 0; r < 16; r++) {
      int sl = i * 32 + (r & 3) + 8 * (r >> 2) + 4 * lk;
      int s = s0 + sl;
      int tok = tokidx[s];
      if (tok < 0) continue;
      out[(long long)tok * H + n] =
          (float)((double)x2[(long long)tok * H + n] + (double)acc[i][r] * invd[sl]);
    }
  }
}

// ---------------- launch ----------------
// ws layout (bytes):
//   0        partial double[28*1024] (224 KB)
//   229376   wsd double[28]
//   229600   xsd double[4096] (32 KB)
//   262368   eidx int[4096] (16 KB)
//   278752   Mk float[32]
//   278912   meta int[128]  (ntile + tile_e)
//   279424   tokidx int[4608] (18 KB)
//   297856   hsd double[4608] (36.9 KB)
//   1MB      qw int8: 28 x 1MB
//   29MB     xq int8 4MB
//   33MB     qbuf fp32 16MB (q -> attn out h); later hhbuf f32 [4544][1024] (18.6MB, 33..51.6)
//   49MB     Kh ushort 8MB (dead after attn); hq int8 @52..56.7 later (inside)
//   57MB     Kl ushort 8MB (dead after attn)
//   65MB     Vp uint32 16MB (dead after attn); x2 fp32 written here by o-proj
extern "C" void kernel_launch(void* const* d_in, const int* in_sizes, int n_in,
                              void* d_out, int out_size, void* d_ws, size_t ws_size,
                              hipStream_t stream) {
  const float* x   = (const float*)d_in[0];
  const float* qw_ = (const float*)d_in[1];
  const float* kw_ = (const float*)d_in[2];
  const float* vw_ = (const float*)d_in[3];
  const float* ow_ = (const float*)d_in[4];
  const float* ln1 = (const float*)d_in[5];
  const float* ln2 = (const float*)d_in[6];
  const float* rw  = (const float*)d_in[7];
  const float* gw  = (const float*)d_in[8];
  const float* uw  = (const float*)d_in[9];
  const float* dw  = (const float*)d_in[10];
  float* out = (float*)d_out;

  uint8_t* ws = (uint8_t*)d_ws;
  double* partial = (double*)ws;
  double* wsd    = (double*)(ws + 229376);
  double* xsd    = (double*)(ws + 229600);
  int*    eidx   = (int*)(ws + 262368);
  float*  Mk     = (float*)(ws + 278752);
  int*    meta   = (int*)(ws + 278912);
  int*    tokidx = (int*)(ws + 279424);
  double* hsd    = (double*)(ws + 297856);
  int8_t* qw     = (int8_t*)(ws + (1ull << 20));
  int8_t* xq     = (int8_t*)(ws + (29ull << 20));
  float*  qbuf   = (float*)(ws + (33ull << 20));
  float*  hhbuf  = (float*)(ws + (33ull << 20));   // aliases qbuf (dead by then)
  unsigned short* Kh = (unsigned short*)(ws + (49ull << 20));
  unsigned short* Kl = (unsigned short*)(ws + (57ull << 20));
  int8_t* hq     = (int8_t*)(ws + (52ull << 20));  // inside dead Kh region (post-attn)
  unsigned int* Vp = (unsigned int*)(ws + (65ull << 20));
  float*  vbuf   = (float*)(ws + (65ull << 20));   // x2 overwrites dead Vp post-attn

  // weight quantization (deterministic fp64 scales)
  k_absum<<<28 * 1024, 256, 0, stream>>>(qw_, kw_, vw_, ow_, gw, uw, dw, partial);
  k_wscale<<<28, 256, 0, stream>>>(partial, wsd);
  k_quantw<<<28 * 1024, 256, 0, stream>>>(qw_, kw_, vw_, ow_, gw, uw, dw, wsd, qw);

  // attention input: rmsnorm + act_quant
  k_rms1<<<NTOK, 256, 0, stream>>>(x, ln1, xq, xsd);
  // q/k/v projections fused; k/v written in attention-native packed formats
  k_gemm3<<<dim3(8, 32, 3), 256, 0, stream>>>(xq, xsd, qw, wsd, qbuf, Kh, Kl, Vp);
  // causal flash attention (async-stage prefetch, exp2 softmax, pair-exact PV)
  k_knorm<<<32, 256, 0, stream>>>(Kh, Kl, Mk);
  k_attn<<<dim3(512), 512, 0, stream>>>(qbuf, Kh, Kl, Vp, qbuf, Mk);
  // o projection with residual: x2 = x + bitlinear(h, o_w) -> vbuf (BM=64, 2/CU)
  k_actq<<<NTOK, 256, 0, stream>>>(qbuf, xq, xsd);
  k_gemm<<<dim3(8, 64), 256, 0, stream>>>(xq, xsd, qw + (3 << 20), wsd, 3, x, vbuf);
  // MoE: rmsnorm2 + router argmax + act_quant, then expert-gathered GEMMs
  k_rms2_router<<<NTOK, 256, 0, stream>>>(vbuf, ln2, rw, xq, xsd, eidx);
  k_route<<<1, 256, 0, stream>>>(eidx, meta, tokidx);
  k_moe_gu<<<dim3(8, 71), 256, 0, stream>>>(xq, xsd, qw, wsd, meta, tokidx, hhbuf);
  k_hh_actq<<<4544, 256, 0, stream>>>(hhbuf, meta, tokidx, hq, hsd);
  k_moe_down<<<dim3(8, 71), 256, 0, stream>>>(hq, hsd, qw, wsd, meta, tokidx, vbuf, out);
}